// Round 15
// baseline (12622.564 us; speedup 1.0000x reference)
//
#include <hip/hip_runtime.h>
#include <stdint.h>
#include <stddef.h>

// GRU (B=32, T=2048, I=H=512, fp32 in/out).
// Phase 1 (MFMA GEMM): gz|gr -> fp16 INTO d_out (row-aliased); gh -> d_ws.
// Phase 2 (R15): persistent scan, 256 WGs = 16 slices x 16 pairs; pair p =
//   batches (p, p+16) processed FUSED in one phase-set per step:
//   one combine-spin (34 tagged words), one z/r GEMV pass with each weight
//   b128 read ONCE for both batches, one reduce, one candidate + dual publish.
//   3 barriers / 2 batch-steps (R14 paid 6 + 2 spins + 2x weight reads).
//   Exchange: P slice-major coalesced u32 {tag16|fp16} (R14's fix: agent
//   stores write through at line granularity), z u64 {tag32|f32}; agent scope
//   only (R9/R10: consumer-cacheable polls livelock). Parity double-buffer;
//   overwrite gated transitively by peers' combine-before-publish + barriers.
// Fallback (!gh_mode): R8 scalar scan.

#define AGENT __HIP_MEMORY_SCOPE_AGENT

typedef _Float16 h2v __attribute__((ext_vector_type(2)));
typedef _Float16 half8 __attribute__((ext_vector_type(8)));
typedef float f32x4 __attribute__((ext_vector_type(4)));

__device__ __forceinline__ uint32_t pk2u(float a, float b) {
  h2v r; r[0] = (_Float16)a; r[1] = (_Float16)b;
  return __builtin_bit_cast(uint32_t, r);
}
__device__ __forceinline__ h2v bc2(uint32_t u) { return __builtin_bit_cast(h2v, u); }
__device__ __forceinline__ float dot2f(h2v a, h2v b, float c) {
#if __has_builtin(__builtin_amdgcn_fdot2)
  return __builtin_amdgcn_fdot2(a, b, c, false);
#else
  return fmaf((float)a[1], (float)b[1], fmaf((float)a[0], (float)b[0], c));
#endif
}
__device__ __forceinline__ float sigmoidf_(float x) { return 1.0f / (1.0f + __expf(-x)); }
__device__ __forceinline__ float tanhf_(float x) { return 1.0f - 2.0f / (1.0f + __expf(2.0f * x)); }

__device__ __forceinline__ uint32_t ald32(const uint32_t* p) {
  return __hip_atomic_load(p, __ATOMIC_RELAXED, AGENT);
}
__device__ __forceinline__ void ast32(uint32_t* p, uint32_t v) {
  __hip_atomic_store(p, v, __ATOMIC_RELAXED, AGENT);
}
__device__ __forceinline__ uint64_t ald64(const uint64_t* p) {
  return __hip_atomic_load(p, __ATOMIC_RELAXED, AGENT);
}
__device__ __forceinline__ void ast64(uint64_t* p, uint64_t v) {
  __hip_atomic_store(p, v, __ATOMIC_RELAXED, AGENT);
}
__device__ __forceinline__ float f16b2f(uint32_t w) {
  return (float)__builtin_bit_cast(_Float16, (unsigned short)(w & 0xffffu));
}

// ---------------- Phase 1: gate GEMM  [65536 x 512] @ [512 x N*128] -> fp16 ----------------
__global__ __launch_bounds__(256) void gemm_gx(const float* __restrict__ x,
                                               const float* __restrict__ Wx,
                                               const float* __restrict__ bias,
                                               _Float16* gzr,   // [65536][1024] (aliases out)
                                               _Float16* gh,    // [65536][512] in ws (opt)
                                               int nTN) {
  __shared__ alignas(16) _Float16 Alds[128 * 68];
  __shared__ alignas(16) _Float16 Blds[128 * 68];
  const int tid = threadIdx.x;
  const int bid = blockIdx.x;
  const int tm = bid / nTN, tn = bid % nTN;
  const int m0 = tm << 7, n0 = tn << 7;
  const int lane = tid & 63;
  const int wv = tid >> 6, wm = wv >> 1, wn = wv & 1;
  const int l15 = lane & 15, lhi = lane >> 4;
  f32x4 acc[4][4] = {};

  for (int k0 = 0; k0 < 512; k0 += 64) {
#pragma unroll
    for (int r = 0; r < 8; ++r) {
      int m = r * 16 + (tid >> 4);
      int k = (tid & 15) * 4;
      float4 v = *(const float4*)&x[(size_t)(m0 + m) * 512 + k0 + k];
      union { _Float16 h[4]; uint2 u; } cv;
      cv.h[0] = (_Float16)v.x; cv.h[1] = (_Float16)v.y;
      cv.h[2] = (_Float16)v.z; cv.h[3] = (_Float16)v.w;
      *(uint2*)&Alds[m * 68 + k] = cv.u;
    }
#pragma unroll
    for (int u = 0; u < 8; ++u) {
      int n = tid & 127;
      int k = (tid >> 7) * 32 + u * 4;
      int ng = n0 + n;
      const float* wp = Wx + ((size_t)(ng >> 9) << 18) + (size_t)(k0 + k) * 512 + (ng & 511);
      union { _Float16 h[4]; uint2 u2; } cv;
      cv.h[0] = (_Float16)wp[0];    cv.h[1] = (_Float16)wp[512];
      cv.h[2] = (_Float16)wp[1024]; cv.h[3] = (_Float16)wp[1536];
      *(uint2*)&Blds[n * 68 + k] = cv.u2;
    }
    __syncthreads();
#pragma unroll
    for (int kk = 0; kk < 2; ++kk) {
      int q = kk * 4 + lhi;
      half8 af[4], bf[4];
#pragma unroll
      for (int fm = 0; fm < 4; ++fm) {
        const _Float16* pa = &Alds[(wm * 64 + fm * 16 + l15) * 68 + q * 8];
        union { uint2 u[2]; half8 h; } cv;
        cv.u[0] = *(const uint2*)pa; cv.u[1] = *(const uint2*)(pa + 4);
        af[fm] = cv.h;
      }
#pragma unroll
      for (int fn = 0; fn < 4; ++fn) {
        const _Float16* pb = &Blds[(wn * 64 + fn * 16 + l15) * 68 + q * 8];
        union { uint2 u[2]; half8 h; } cv;
        cv.u[0] = *(const uint2*)pb; cv.u[1] = *(const uint2*)(pb + 4);
        bf[fn] = cv.h;
      }
#pragma unroll
      for (int fm = 0; fm < 4; ++fm)
#pragma unroll
        for (int fn = 0; fn < 4; ++fn)
          acc[fm][fn] = __builtin_amdgcn_mfma_f32_16x16x32_f16(af[fm], bf[fn], acc[fm][fn], 0, 0, 0);
    }
    __syncthreads();
  }
#pragma unroll
  for (int fn = 0; fn < 4; ++fn) {
    int col = n0 + wn * 64 + fn * 16 + l15;
    float bv = bias[col];
#pragma unroll
    for (int fm = 0; fm < 4; ++fm) {
#pragma unroll
      for (int q2 = 0; q2 < 4; ++q2) {
        int row = m0 + wm * 64 + fm * 16 + lhi * 4 + q2;
        _Float16 val = (_Float16)(acc[fm][fn][q2] + bv);
        if (n0 < 1024) gzr[(size_t)row * 1024 + col] = val;
        else           gh[(size_t)row * 512 + (col - 1024)] = val;
      }
    }
  }
}

// ---------------- Phase 2 (R15): fused S=16 x D=2 persistent scan ----------------
__device__ __forceinline__ bool tagsok2(const uint32_t pvA[16], const uint32_t pvB[16],
                                        uint64_t zvA, uint64_t zvB, uint32_t want) {
  bool ok = ((uint32_t)(zvA >> 32) == want) && ((uint32_t)(zvB >> 32) == want);
#pragma unroll
  for (int q = 0; q < 16; ++q) {
    ok &= ((pvA[q] >> 16) == want);
    ok &= ((pvB[q] >> 16) == want);
  }
  return ok;
}

__global__ __launch_bounds__(512) void gru_scan2(
    const _Float16* gzr,            // [65536][1024] (aliases out!)
    const _Float16* ghg,            // [65536][512]
    const float* __restrict__ Wh,   // [3][512][512]
    float* out,                     // [32][2048][512] + [32][512]
    uint32_t* __restrict__ Pbuf,    // [2][32][16 slice][512 col] u32 {tag16|fp16}
    uint64_t* __restrict__ zbuf) {  // [2][32][512] u64 {tag32|f32}
  __shared__ alignas(16) _Float16 wzK[2 * 64 * 32 * 8];  // [g][kc][col][8] : 64KB
  __shared__ alignas(16) _Float16 hA[512], hB[512];
  __shared__ alignas(16) _Float16 rhA[32], rhB[32];
  __shared__ alignas(16) float zrp[2][2][16][32];        // [gate][batch][sub][col] : 8KB

  const int T = threadIdx.x;
  const int bid = blockIdx.x;          // 0..255
  const int s = bid >> 4;              // slice 0..15 -> cols [s*32, s*32+32)
  const int p = bid & 15;              // pair 0..15 (16 WGs of pair p share one XCD)
  const int c0 = s * 32;
  const int bA = p, bB = p + 16;
  const int j = T & 31, sub = T >> 5;  // z/r: col-in-slice, K-16th

  // ---- z/r weight fill: wzK[g][kc][j][e] = W_g[kc*8+e][c0+j] ----
  for (int g = 0; g < 2; ++g) {
    const float* W = Wh + (size_t)g * 262144;
    for (int kc = sub; kc < 64; kc += 16) {
#pragma unroll
      for (int e = 0; e < 8; ++e) {
        int k = kc * 8 + e;
        wzK[((g * 64 + kc) * 32 + j) * 8 + e] = (_Float16)W[(size_t)k * 512 + c0 + j];
      }
    }
  }
  // ---- candidate weights: 16 u32/thread (K rows = own cols c0..c0+31) ----
  uint32_t wh2[16];
  {
    const float* Whh = Wh + 524288;
#pragma unroll
    for (int i = 0; i < 16; ++i) {
      int kk = c0 + 2 * i;
      wh2[i] = pk2u(Whh[(size_t)kk * 512 + T], Whh[(size_t)(kk + 1) * 512 + T]);
    }
  }
  hA[T] = (_Float16)0.0f;
  hB[T] = (_Float16)0.0f;
  float hregA = 0.f, hregB = 0.f;

  const size_t rbA = (size_t)bA * 2048, rbB = (size_t)bB * 2048;
  float gzA_p = 0.f, grA_p = 0.f, gzB_p = 0.f, grB_p = 0.f;
  float gzA_c = 0.f, grA_c = 0.f, gzB_c = 0.f, grB_c = 0.f;
  float ghA_p, ghB_p, ghA_c = 0.f, ghB_c = 0.f;
  if (T < 32) {
    gzA_p = (float)gzr[rbA * 1024 + c0 + T];
    gzB_p = (float)gzr[rbB * 1024 + c0 + T];
  } else if (T < 64) {
    grA_p = (float)gzr[rbA * 1024 + 512 + c0 + (T - 32)];
    grB_p = (float)gzr[rbB * 1024 + 512 + c0 + (T - 32)];
  }
  ghA_p = (float)ghg[rbA * 512 + T];
  ghB_p = (float)ghg[rbB * 512 + T];

  // exchange pointers — SLICE-MAJOR coalesced: P[par][b][slice][col]
  uint32_t* PmA = Pbuf + ((size_t)bA * 16 + s) * 512 + T;   // + par*262144
  uint32_t* PmB = Pbuf + ((size_t)bB * 16 + s) * 512 + T;
  const uint32_t* PrA = Pbuf + (size_t)bA * 8192 + T;       // slice q at +q*512
  const uint32_t* PrB = Pbuf + (size_t)bB * 8192 + T;
  uint64_t* zmA = zbuf + (size_t)bA * 512 + c0 + (T & 31);  // + par*16384 (T<32 publish)
  uint64_t* zmB = zbuf + (size_t)bB * 512 + c0 + (T & 31);
  const uint64_t* zrdA = zbuf + (size_t)bA * 512 + T;
  const uint64_t* zrdB = zbuf + (size_t)bB * 512 + T;

  uint32_t pvA[16], pvB[16];
  uint64_t zvA = 0, zvB = 0;
#pragma unroll
  for (int q = 0; q < 16; ++q) { pvA[q] = 0; pvB[q] = 0; }

  for (int t = 0; t < 2048; ++t) {
    const size_t poC = ((t - 1) & 1) ? 262144 : 0;  // combine parity (step t-1)
    const size_t zoC = ((t - 1) & 1) ? 16384 : 0;
    const size_t poN = (t & 1) ? 262144 : 0;        // publish parity (step t)
    const size_t zoN = (t & 1) ? 16384 : 0;
    const uint32_t want = (uint32_t)t;              // tag of step t-1 data
    const uint32_t tagN = (uint32_t)(t + 1);

    // ---- fused combine (both batches), step t-1 ----
    if (t > 0) {
      while (!tagsok2(pvA, pvB, zvA, zvB, want)) {
        __builtin_amdgcn_s_sleep(1);
        if ((uint32_t)(zvA >> 32) != want) zvA = ald64(zrdA + zoC);
        if ((uint32_t)(zvB >> 32) != want) zvB = ald64(zrdB + zoC);
#pragma unroll
        for (int q = 0; q < 16; ++q) {
          if ((pvA[q] >> 16) != want) pvA[q] = ald32(PrA + poC + (size_t)q * 512);
          if ((pvB[q] >> 16) != want) pvB[q] = ald32(PrB + poC + (size_t)q * 512);
        }
      }
      float hsA = 0.f, hsB = 0.f;
#pragma unroll
      for (int q = 0; q < 16; ++q) { hsA += f16b2f(pvA[q]); hsB += f16b2f(pvB[q]); }
      float zfA = __uint_as_float((uint32_t)zvA);
      float zfB = __uint_as_float((uint32_t)zvB);
      float hnA = fmaf(zfA, tanhf_(ghA_c + hsA) - hregA, hregA);
      float hnB = fmaf(zfB, tanhf_(ghB_c + hsB) - hregB, hregB);
      if (sub == s) {
        out[(rbA + (t - 1)) * 512 + T] = hnA;
        out[(rbB + (t - 1)) * 512 + T] = hnB;
      }
      hregA = hnA; hregB = hnB;
      hA[T] = (_Float16)hnA;
      hB[T] = (_Float16)hnB;
    }
    gzA_c = gzA_p; grA_c = grA_p; ghA_c = ghA_p;
    gzB_c = gzB_p; grB_c = grB_p; ghB_c = ghB_p;
    __syncthreads();  // B1: hA,hB visible
    if (t < 2047) {
      size_t r1A = rbA + t + 1, r1B = rbB + t + 1;
      if (T < 32) {
        gzA_p = (float)gzr[r1A * 1024 + c0 + T];
        gzB_p = (float)gzr[r1B * 1024 + c0 + T];
      } else if (T < 64) {
        grA_p = (float)gzr[r1A * 1024 + 512 + c0 + (T - 32)];
        grB_p = (float)gzr[r1B * 1024 + 512 + c0 + (T - 32)];
      }
      ghA_p = (float)ghg[r1A * 512 + T];
      ghB_p = (float)ghg[r1B * 512 + T];
    }

    // ---- fused z/r GEMV: each weight b128 read once, applied to hA and hB ----
    {
      float zaA = 0.f, raA = 0.f, zaB = 0.f, raB = 0.f;
#pragma unroll
      for (int cc = 0; cc < 4; ++cc) {
        int kc = sub * 4 + cc;
        uint4 wz = *(const uint4*)&wzK[(kc * 32 + j) * 8];         // stride-16B, conflict-free
        uint4 wr = *(const uint4*)&wzK[((64 + kc) * 32 + j) * 8];
        uint4 huA = *(const uint4*)&hA[kc * 8];                    // broadcast
        uint4 huB = *(const uint4*)&hB[kc * 8];
        zaA = dot2f(bc2(huA.x), bc2(wz.x), zaA); zaA = dot2f(bc2(huA.y), bc2(wz.y), zaA);
        zaA = dot2f(bc2(huA.z), bc2(wz.z), zaA); zaA = dot2f(bc2(huA.w), bc2(wz.w), zaA);
        raA = dot2f(bc2(huA.x), bc2(wr.x), raA); raA = dot2f(bc2(huA.y), bc2(wr.y), raA);
        raA = dot2f(bc2(huA.z), bc2(wr.z), raA); raA = dot2f(bc2(huA.w), bc2(wr.w), raA);
        zaB = dot2f(bc2(huB.x), bc2(wz.x), zaB); zaB = dot2f(bc2(huB.y), bc2(wz.y), zaB);
        zaB = dot2f(bc2(huB.z), bc2(wz.z), zaB); zaB = dot2f(bc2(huB.w), bc2(wz.w), zaB);
        raB = dot2f(bc2(huB.x), bc2(wr.x), raB); raB = dot2f(bc2(huB.y), bc2(wr.y), raB);
        raB = dot2f(bc2(huB.z), bc2(wr.z), raB); raB = dot2f(bc2(huB.w), bc2(wr.w), raB);
      }
      zrp[0][0][sub][j] = zaA;
      zrp[1][0][sub][j] = raA;
      zrp[0][1][sub][j] = zaB;
      zrp[1][1][sub][j] = raB;
    }
    __syncthreads();  // B2: zrp ready
    if (T < 64) {
      const int g = T >> 5, jj = T & 31;
      float sA = 0.f, sB = 0.f;
#pragma unroll
      for (int q = 0; q < 16; ++q) {
        sA += zrp[g][0][q][jj];
        sB += zrp[g][1][q][jj];
      }
      if (g == 0) {
        float zA = sigmoidf_(sA + gzA_c);
        float zB = sigmoidf_(sB + gzB_c);
        ast64(zmA + zoN, ((uint64_t)tagN << 32) | (uint32_t)__float_as_uint(zA));
        ast64(zmB + zoN, ((uint64_t)tagN << 32) | (uint32_t)__float_as_uint(zB));
      } else {
        float rA = sigmoidf_(sA + grA_c);
        float rB = sigmoidf_(sB + grB_c);
        rhA[jj] = (_Float16)(rA * (float)hA[c0 + jj]);
        rhB[jj] = (_Float16)(rB * (float)hB[c0 + jj]);
      }
    }
    __syncthreads();  // B3: rhA,rhB ready
    {  // fused candidate: P[T] = rh(own cols) @ Whh for both batches -> publish
      float paA = 0.f, paB = 0.f;
#pragma unroll
      for (int i = 0; i < 8; ++i) {
        uint2 ruA = *(const uint2*)&rhA[4 * i];  // broadcast
        uint2 ruB = *(const uint2*)&rhB[4 * i];
        paA = dot2f(bc2(ruA.x), bc2(wh2[2 * i]), paA);
        paA = dot2f(bc2(ruA.y), bc2(wh2[2 * i + 1]), paA);
        paB = dot2f(bc2(ruB.x), bc2(wh2[2 * i]), paB);
        paB = dot2f(bc2(ruB.y), bc2(wh2[2 * i + 1]), paB);
      }
      unsigned short pbA = __builtin_bit_cast(unsigned short, (_Float16)paA);
      unsigned short pbB = __builtin_bit_cast(unsigned short, (_Float16)paB);
      ast32(PmA + poN, (tagN << 16) | (uint32_t)pbA);
      ast32(PmB + poN, (tagN << 16) | (uint32_t)pbB);
    }
    // pre-issue next combine loads (tag t+1, parity poN)
    zvA = ald64(zrdA + zoN);
    zvB = ald64(zrdB + zoN);
#pragma unroll
    for (int q = 0; q < 16; ++q) {
      pvA[q] = ald32(PrA + poN + (size_t)q * 512);
      pvB[q] = ald32(PrB + poN + (size_t)q * 512);
    }
    __builtin_amdgcn_sched_barrier(0);
  }

  // ---- epilogue: combine step 2047 (parity 1, tag 2048), both batches ----
  {
    const uint32_t want = 2048u;
    while (!tagsok2(pvA, pvB, zvA, zvB, want)) {
      __builtin_amdgcn_s_sleep(1);
      if ((uint32_t)(zvA >> 32) != want) zvA = ald64(zrdA + 16384);
      if ((uint32_t)(zvB >> 32) != want) zvB = ald64(zrdB + 16384);
#pragma unroll
      for (int q = 0; q < 16; ++q) {
        if ((pvA[q] >> 16) != want) pvA[q] = ald32(PrA + 262144 + (size_t)q * 512);
        if ((pvB[q] >> 16) != want) pvB[q] = ald32(PrB + 262144 + (size_t)q * 512);
      }
    }
    float hsA = 0.f, hsB = 0.f;
#pragma unroll
    for (int q = 0; q < 16; ++q) { hsA += f16b2f(pvA[q]); hsB += f16b2f(pvB[q]); }
    float zfA = __uint_as_float((uint32_t)zvA);
    float zfB = __uint_as_float((uint32_t)zvB);
    float hnA = fmaf(zfA, tanhf_(ghA_c + hsA) - hregA, hregA);
    float hnB = fmaf(zfB, tanhf_(ghB_c + hsB) - hregB, hregB);
    if (sub == s) {
      out[(rbA + 2047) * 512 + T] = hnA;
      out[(rbB + 2047) * 512 + T] = hnB;
      out[(size_t)32 * 2048 * 512 + (size_t)bA * 512 + T] = hnA;
      out[(size_t)32 * 2048 * 512 + (size_t)bB * 512 + T] = hnB;
    }
  }
}

// ---------------- Fallback scan (R8 scalar, !gh_mode) ----------------
__global__ __launch_bounds__(512) void gru_scan_fb(
    const float* __restrict__ x, const float* __restrict__ Wx,
    const float* __restrict__ Wh, const float* __restrict__ bias,
    const _Float16* gzr, float* out,
    uint64_t* __restrict__ Pbuf, uint64_t* __restrict__ zbuf) {
  __shared__ alignas(16) float zrp[2][8][64];
  __shared__ alignas(16) _Float16 wzrL[2 * 64 * 516];
  __shared__ alignas(16) _Float16 h16[512];
  __shared__ alignas(16) _Float16 rh16[64];
  __shared__ alignas(16) _Float16 x16s[64];

  const int T = threadIdx.x;
  const int bid = blockIdx.x;
  const int xcd = bid & 7, ii = bid >> 3;
  const int batch = xcd * 4 + (ii >> 3);
  const int slice = ii & 7;
  const int wv = T >> 6, ln = T & 63, n = T;
  {
    const int cc = T & 63, kb = T >> 6;
#pragma unroll 4
    for (int g = 0; g < 2; ++g) {
      const float* W = Wh + (size_t)g * 262144 + slice * 64 + cc;
      for (int i = 0; i < 64; ++i) {
        int k = kb + 8 * i;
        wzrL[(g * 64 + cc) * 516 + k] = (_Float16)W[(size_t)k * 512];
      }
    }
  }
  uint32_t wh2[32], wx2[32];
  {
    const float* Whh = Wh + 524288;
    const float* Wxh = Wx + 524288;
#pragma unroll
    for (int jj = 0; jj < 32; ++jj) {
      int kk = slice * 64 + 2 * jj;
      wh2[jj] = pk2u(Whh[(size_t)kk * 512 + n], Whh[(size_t)(kk + 1) * 512 + n]);
      wx2[jj] = pk2u(Wxh[(size_t)kk * 512 + n], Wxh[(size_t)(kk + 1) * 512 + n]);
    }
  }
  const float bh = bias[1024 + n];
  float hreg = 0.0f;
  h16[T] = (_Float16)0.0f;
  const size_t rowbase = (size_t)batch * 2048;
  float gz_p = 0.f, gr_p = 0.f, gz_cur = 0.f, gr_cur = 0.f, x_p = 0.f;
  if (T < 64)       gz_p = (float)gzr[rowbase * 1024 + slice * 64 + T];
  else if (T < 128) gr_p = (float)gzr[rowbase * 1024 + 512 + slice * 64 + (T - 64)];
  if (T < 64) x_p = x[rowbase * 512 + slice * 64 + T];

  uint64_t* Pmine = Pbuf + ((size_t)batch * 8 + slice) * 512 + n;
  const uint64_t* Pread = Pbuf + ((size_t)batch * 8) * 512 + n;
  uint64_t* zmine = zbuf + (size_t)batch * 512 + slice * 64 + ln;
  const uint64_t* zread = zbuf + (size_t)batch * 512 + n;

  for (int t = 0; t < 2048; ++t) {
    if (t > 0) {
      const size_t po = ((t - 1) & 1) ? 131072 : 0;
      const size_t zo = ((t - 1) & 1) ? 16384 : 0;
      const uint32_t want = (uint32_t)t;
      uint64_t v[8];
#pragma unroll
      for (int g = 0; g < 8; ++g) v[g] = ald64(Pread + po + (size_t)g * 512);
      uint64_t zv = ald64(zread + zo);
      for (;;) {
        bool ok = true;
        if ((uint32_t)(zv >> 32) != want) { zv = ald64(zread + zo); ok = false; }
#pragma unroll
        for (int g = 0; g < 8; ++g)
          if ((uint32_t)(v[g] >> 32) != want) { v[g] = ald64(Pread + po + (size_t)g * 512); ok = false; }
        if (ok) break;
        __builtin_amdgcn_s_sleep(1);
      }
      float hsum = 0.f;
#pragma unroll
      for (int g = 0; g < 8; ++g) hsum += __uint_as_float((uint32_t)v[g]);
      float zf = __uint_as_float((uint32_t)zv);
      float htil = tanhf_(bh + hsum);
      float hn = fmaf(zf, htil - hreg, hreg);
      if (slice == 0) out[(rowbase + (t - 1)) * 512 + n] = hn;
      hreg = hn;
      h16[T] = (_Float16)hn;
    }
    gz_cur = gz_p; gr_cur = gr_p;
    if (T < 64) x16s[T] = (_Float16)x_p;
    __syncthreads();
    if (t < 2047) {
      size_t r1 = rowbase + t + 1;
      if (T < 64)       gz_p = (float)gzr[r1 * 1024 + slice * 64 + T];
      else if (T < 128) gr_p = (float)gzr[r1 * 1024 + 512 + slice * 64 + (T - 64)];
      if (T < 64) x_p = x[r1 * 512 + slice * 64 + T];
    }
    float za = 0.f, ra = 0.f;
    {
      const _Float16* wzp = &wzrL[ln * 516 + 64 * wv];
      const _Float16* wrp = &wzrL[(64 + ln) * 516 + 64 * wv];
      const _Float16* hp = &h16[64 * wv];
#pragma unroll
      for (int jj = 0; jj < 16; ++jj) {
        uint2 wzu = *(const uint2*)(wzp + 4 * jj);
        uint2 wru = *(const uint2*)(wrp + 4 * jj);
        uint2 hu = *(const uint2*)(hp + 4 * jj);
        za = dot2f(bc2(hu.x), bc2(wzu.x), za);
        za = dot2f(bc2(hu.y), bc2(wzu.y), za);
        ra = dot2f(bc2(hu.x), bc2(wru.x), ra);
        ra = dot2f(bc2(hu.y), bc2(wru.y), ra);
      }
    }
    zrp[0][wv][ln] = za;
    zrp[1][wv][ln] = ra;
    __syncthreads();
    const size_t po = (t & 1) ? 131072 : 0;
    const size_t zo = (t & 1) ? 16384 : 0;
    const uint64_t tagw = ((uint64_t)(uint32_t)(t + 1)) << 32;
    if (T < 128) {
      const int g = T >> 6, cc = T & 63;
      float sum = 0.f;
#pragma unroll
      for (int s2 = 0; s2 < 8; ++s2) sum += zrp[g][s2][cc];
      if (g == 0) {
        float z = sigmoidf_(sum + gz_cur);
        ast64(zmine + zo, tagw | (uint32_t)__float_as_uint(z));
      } else {
        float r = sigmoidf_(sum + gr_cur);
        rh16[cc] = (_Float16)(r * (float)h16[slice * 64 + cc]);
      }
    }
    __syncthreads();
    float pa = 0.f;
#pragma unroll
    for (int jj = 0; jj < 16; ++jj) {
      uint2 ru = *(const uint2*)&rh16[4 * jj];
      pa = dot2f(bc2(ru.x), bc2(wh2[2 * jj]), pa);
      pa = dot2f(bc2(ru.y), bc2(wh2[2 * jj + 1]), pa);
    }
#pragma unroll
    for (int jj = 0; jj < 16; ++jj) {
      uint2 xu = *(const uint2*)&x16s[4 * jj];
      pa = dot2f(bc2(xu.x), bc2(wx2[2 * jj]), pa);
      pa = dot2f(bc2(xu.y), bc2(wx2[2 * jj + 1]), pa);
    }
    ast64(Pmine + po, tagw | (uint32_t)__float_as_uint(pa));
    __syncthreads();
  }
  {
    const uint32_t want = 2048u;
    uint64_t v[8];
#pragma unroll
    for (int g = 0; g < 8; ++g) v[g] = ald64(Pread + 131072 + (size_t)g * 512);
    uint64_t zv = ald64(zread + 16384);
    for (;;) {
      bool ok = true;
      if ((uint32_t)(zv >> 32) != want) { zv = ald64(zread + 16384); ok = false; }
#pragma unroll
      for (int g = 0; g < 8; ++g)
        if ((uint32_t)(v[g] >> 32) != want) { v[g] = ald64(Pread + 131072 + (size_t)g * 512); ok = false; }
      if (ok) break;
      __builtin_amdgcn_s_sleep(1);
    }
    float hsum = 0.f;
#pragma unroll
    for (int g = 0; g < 8; ++g) hsum += __uint_as_float((uint32_t)v[g]);
    float zf = __uint_as_float((uint32_t)zv);
    float htil = tanhf_(bh + hsum);
    float hn = fmaf(zf, htil - hreg, hreg);
    if (slice == 0) {
      out[(rowbase + 2047) * 512 + n] = hn;
      out[(size_t)32 * 2048 * 512 + (size_t)batch * 512 + n] = hn;
    }
  }
}

extern "C" void kernel_launch(void* const* d_in, const int* in_sizes, int n_in,
                              void* d_out, int out_size, void* d_ws, size_t ws_size,
                              hipStream_t stream) {
  (void)in_sizes; (void)n_in; (void)out_size;
  const float* x    = (const float*)d_in[0];
  const float* Wx   = (const float*)d_in[1];
  const float* Wh   = (const float*)d_in[2];
  const float* bias = (const float*)d_in[3];
  float* out = (float*)d_out;
  char* ws = (char*)d_ws;

  // gh_mode layout: Pbuf u32 [2][32][16][512] = 2 MB | zbuf u64 [2][32][512] = 256 KB | gh @ 2621440
  // fallback layout: Pbuf u64 2 MB | zbuf u64 @ 2097152
  uint32_t* Pbuf2 = (uint32_t*)ws;
  uint64_t* zbuf2 = (uint64_t*)(ws + 2097152);
  uint64_t* PbufF = (uint64_t*)ws;
  uint64_t* zbufF = (uint64_t*)(ws + 2097152);
  _Float16* gh    = (_Float16*)(ws + 2621440);

  hipMemsetAsync(ws, 0, 2621440, stream);  // reset exchange tags (replay-safe)
  const bool gh_mode = ws_size >= (size_t)2621440 + 67108864ull;
  if (gh_mode) {
    gemm_gx<<<512 * 12, 256, 0, stream>>>(x, Wx, bias, (_Float16*)d_out, gh, 12);
    gru_scan2<<<256, 512, 0, stream>>>((const _Float16*)d_out, gh, Wh, out,
                                       Pbuf2, zbuf2);
  } else {
    gemm_gx<<<512 * 8, 256, 0, stream>>>(x, Wx, bias, (_Float16*)d_out, gh, 8);
    gru_scan_fb<<<256, 512, 0, stream>>>(x, Wx, Wh, bias, (const _Float16*)d_out,
                                         out, PbufF, zbufF);
  }
}

// Round 16
// 7092.312 us; speedup vs baseline: 1.7798x; 1.7798x over previous
//
#include <hip/hip_runtime.h>
#include <stdint.h>
#include <stddef.h>

// GRU (B=32, T=2048, I=H=512, fp32 in/out).
// Phase 1 (MFMA GEMM): gz|gr -> fp16 INTO d_out (row-aliased); gh -> d_ws.
// Phase 2 (R16): persistent scan, 256 WGs = 8 slices x 32 batches, D=1
//   (wall = 2048 x per-step critical path; R14/R15 proved batch-multiplexing
//   can't beat D=1 if the step is lean). Per-step cuts vs R8 (3.47us):
//   - conflict-free b128 weight LDS [g][cc][col][sub][8] (R14's 0-conflict
//     pattern): 24 b128/thread vs 48 b64.
//   - wave-local shuffle z/r reduce (col=T>>3, sub=T&7): no zrp LDS, 2
//     barriers/step instead of 4 (transitively safe: writers of step t+1
//     pass B1(t+1) only after all readers of step t finished).
//   - fp16 P exchange u32 {tag16|fp16}, slice-major coalesced (R14-proven).
//   Exchange agent-scope tagged only (R9/R10: cached polls livelock).
// Fallback (!gh_mode): R8 scalar scan.

#define AGENT __HIP_MEMORY_SCOPE_AGENT

typedef _Float16 h2v __attribute__((ext_vector_type(2)));
typedef _Float16 half8 __attribute__((ext_vector_type(8)));
typedef float f32x4 __attribute__((ext_vector_type(4)));

__device__ __forceinline__ uint32_t pk2u(float a, float b) {
  h2v r; r[0] = (_Float16)a; r[1] = (_Float16)b;
  return __builtin_bit_cast(uint32_t, r);
}
__device__ __forceinline__ h2v bc2(uint32_t u) { return __builtin_bit_cast(h2v, u); }
__device__ __forceinline__ float dot2f(h2v a, h2v b, float c) {
#if __has_builtin(__builtin_amdgcn_fdot2)
  return __builtin_amdgcn_fdot2(a, b, c, false);
#else
  return fmaf((float)a[1], (float)b[1], fmaf((float)a[0], (float)b[0], c));
#endif
}
__device__ __forceinline__ float sigmoidf_(float x) { return 1.0f / (1.0f + __expf(-x)); }
__device__ __forceinline__ float tanhf_(float x) { return 1.0f - 2.0f / (1.0f + __expf(2.0f * x)); }

__device__ __forceinline__ uint32_t ald32(const uint32_t* p) {
  return __hip_atomic_load(p, __ATOMIC_RELAXED, AGENT);
}
__device__ __forceinline__ void ast32(uint32_t* p, uint32_t v) {
  __hip_atomic_store(p, v, __ATOMIC_RELAXED, AGENT);
}
__device__ __forceinline__ uint64_t ald64(const uint64_t* p) {
  return __hip_atomic_load(p, __ATOMIC_RELAXED, AGENT);
}
__device__ __forceinline__ void ast64(uint64_t* p, uint64_t v) {
  __hip_atomic_store(p, v, __ATOMIC_RELAXED, AGENT);
}
__device__ __forceinline__ float f16b2f(uint32_t w) {
  return (float)__builtin_bit_cast(_Float16, (unsigned short)(w & 0xffffu));
}

// ---------------- Phase 1: gate GEMM  [65536 x 512] @ [512 x N*128] -> fp16 ----------------
__global__ __launch_bounds__(256) void gemm_gx(const float* __restrict__ x,
                                               const float* __restrict__ Wx,
                                               const float* __restrict__ bias,
                                               _Float16* gzr,   // [65536][1024] (aliases out)
                                               _Float16* gh,    // [65536][512] in ws (opt)
                                               int nTN) {
  __shared__ alignas(16) _Float16 Alds[128 * 68];
  __shared__ alignas(16) _Float16 Blds[128 * 68];
  const int tid = threadIdx.x;
  const int bid = blockIdx.x;
  const int tm = bid / nTN, tn = bid % nTN;
  const int m0 = tm << 7, n0 = tn << 7;
  const int lane = tid & 63;
  const int wv = tid >> 6, wm = wv >> 1, wn = wv & 1;
  const int l15 = lane & 15, lhi = lane >> 4;
  f32x4 acc[4][4] = {};

  for (int k0 = 0; k0 < 512; k0 += 64) {
#pragma unroll
    for (int r = 0; r < 8; ++r) {
      int m = r * 16 + (tid >> 4);
      int k = (tid & 15) * 4;
      float4 v = *(const float4*)&x[(size_t)(m0 + m) * 512 + k0 + k];
      union { _Float16 h[4]; uint2 u; } cv;
      cv.h[0] = (_Float16)v.x; cv.h[1] = (_Float16)v.y;
      cv.h[2] = (_Float16)v.z; cv.h[3] = (_Float16)v.w;
      *(uint2*)&Alds[m * 68 + k] = cv.u;
    }
#pragma unroll
    for (int u = 0; u < 8; ++u) {
      int n = tid & 127;
      int k = (tid >> 7) * 32 + u * 4;
      int ng = n0 + n;
      const float* wp = Wx + ((size_t)(ng >> 9) << 18) + (size_t)(k0 + k) * 512 + (ng & 511);
      union { _Float16 h[4]; uint2 u2; } cv;
      cv.h[0] = (_Float16)wp[0];    cv.h[1] = (_Float16)wp[512];
      cv.h[2] = (_Float16)wp[1024]; cv.h[3] = (_Float16)wp[1536];
      *(uint2*)&Blds[n * 68 + k] = cv.u2;
    }
    __syncthreads();
#pragma unroll
    for (int kk = 0; kk < 2; ++kk) {
      int q = kk * 4 + lhi;
      half8 af[4], bf[4];
#pragma unroll
      for (int fm = 0; fm < 4; ++fm) {
        const _Float16* pa = &Alds[(wm * 64 + fm * 16 + l15) * 68 + q * 8];
        union { uint2 u[2]; half8 h; } cv;
        cv.u[0] = *(const uint2*)pa; cv.u[1] = *(const uint2*)(pa + 4);
        af[fm] = cv.h;
      }
#pragma unroll
      for (int fn = 0; fn < 4; ++fn) {
        const _Float16* pb = &Blds[(wn * 64 + fn * 16 + l15) * 68 + q * 8];
        union { uint2 u[2]; half8 h; } cv;
        cv.u[0] = *(const uint2*)pb; cv.u[1] = *(const uint2*)(pb + 4);
        bf[fn] = cv.h;
      }
#pragma unroll
      for (int fm = 0; fm < 4; ++fm)
#pragma unroll
        for (int fn = 0; fn < 4; ++fn)
          acc[fm][fn] = __builtin_amdgcn_mfma_f32_16x16x32_f16(af[fm], bf[fn], acc[fm][fn], 0, 0, 0);
    }
    __syncthreads();
  }
#pragma unroll
  for (int fn = 0; fn < 4; ++fn) {
    int col = n0 + wn * 64 + fn * 16 + l15;
    float bv = bias[col];
#pragma unroll
    for (int fm = 0; fm < 4; ++fm) {
#pragma unroll
      for (int q2 = 0; q2 < 4; ++q2) {
        int row = m0 + wm * 64 + fm * 16 + lhi * 4 + q2;
        _Float16 val = (_Float16)(acc[fm][fn][q2] + bv);
        if (n0 < 1024) gzr[(size_t)row * 1024 + col] = val;
        else           gh[(size_t)row * 512 + (col - 1024)] = val;
      }
    }
  }
}

// ---------------- Phase 2 (R16): lean D=1 persistent scan ----------------
__device__ __forceinline__ bool tagsok8(const uint32_t pv[8], uint64_t zv, uint32_t want) {
  bool ok = ((uint32_t)(zv >> 32) == want);
#pragma unroll
  for (int q = 0; q < 8; ++q) ok &= ((pv[q] >> 16) == want);
  return ok;
}

__global__ __launch_bounds__(512) void gru_scan3(
    const _Float16* gzr,            // [65536][1024] (aliases out!)
    const _Float16* ghg,            // [65536][512]
    const float* __restrict__ Wh,   // [3][512][512]
    float* out,                     // [32][2048][512] + [32][512]
    uint32_t* __restrict__ Pbuf,    // [2][32][8 slice][512 col] u32 {tag16|fp16}
    uint64_t* __restrict__ zbuf) {  // [2][32][512] u64 {tag32|f32}
  // wzK[g][cc][col][sub][8]: lane (col,sub) reads 16B at consecutive lane
  // addresses -> conflict-free b128 (R14-verified pattern). 128 KB.
  __shared__ alignas(16) _Float16 wzK[2 * 8 * 64 * 8 * 8];
  __shared__ alignas(16) _Float16 hA[512];   // full h_{t-1}
  __shared__ alignas(16) _Float16 rh[64];    // r*h for own 64 cols

  const int T = threadIdx.x;
  const int bid = blockIdx.x;     // 0..255
  const int s = bid >> 5;         // slice 0..7 -> K rows / z-r cols [s*64, s*64+64)
  const int b = bid & 31;         // batch; bids of batch b = {s*32+b} -> bid%8=b%8 (one XCD)
  const int c = T >> 3, sub = T & 7;
  const int gcol = s * 64 + c;

  // ---- weight fill: wzK entry (g,cc,col,sub)[e] = W_g[(cc*8+sub)*8+e][s*64+col] ----
  for (int g = 0; g < 2; ++g) {
    const float* W = Wh + (size_t)g * 262144;
    for (int idx = T; idx < 4096; idx += 512) {
      int cc = idx >> 9;
      int col = (idx >> 3) & 63;
      int sb = idx & 7;
      int kbase = (cc * 8 + sb) * 8;
      _Float16* dst = &wzK[(((g * 8 + cc) * 64 + col) * 8 + sb) * 8];
#pragma unroll
      for (int e = 0; e < 8; ++e)
        dst[e] = (_Float16)W[(size_t)(kbase + e) * 512 + s * 64 + col];
    }
  }
  // ---- candidate weights: 32 u32/thread (K rows = own 64 cols) ----
  uint32_t wh2[32];
  {
    const float* Whh = Wh + 524288;
#pragma unroll
    for (int i = 0; i < 32; ++i) {
      int kk = s * 64 + 2 * i;
      wh2[i] = pk2u(Whh[(size_t)kk * 512 + T], Whh[(size_t)(kk + 1) * 512 + T]);
    }
  }
  hA[T] = (_Float16)0.0f;
  float hreg = 0.f;

  const size_t rb = (size_t)b * 2048;
  float gh_p, gh_c = 0.f, gz_p = 0.f, gr_p = 0.f, gz_c = 0.f, gr_c = 0.f;
  gh_p = (float)ghg[rb * 512 + T];
  if (sub == 0) {
    gz_p = (float)gzr[rb * 1024 + gcol];
    gr_p = (float)gzr[rb * 1024 + 512 + gcol];
  }

  uint32_t* Pm = Pbuf + ((size_t)b * 8 + s) * 512 + T;  // + par*131072 (coalesced publish)
  const uint32_t* Pr = Pbuf + (size_t)b * 4096 + T;     // slice q at +q*512
  uint64_t* zm = zbuf + (size_t)b * 512 + gcol;         // + par*16384 (sub==0 publish)
  const uint64_t* zrd = zbuf + (size_t)b * 512 + T;

  uint32_t pv[8];
  uint64_t zv = 0;
#pragma unroll
  for (int q = 0; q < 8; ++q) pv[q] = 0;

  for (int t = 0; t < 2048; ++t) {
    const size_t poC = ((t - 1) & 1) ? 131072 : 0;
    const size_t zoC = ((t - 1) & 1) ? 16384 : 0;
    const size_t poN = (t & 1) ? 131072 : 0;
    const size_t zoN = (t & 1) ? 16384 : 0;
    const uint32_t want = (uint32_t)t;
    const uint32_t tagN = (uint32_t)(t + 1);

    // ---- combine step t-1 (pv/zv pre-issued at end of previous iter) ----
    if (t > 0) {
      while (!tagsok8(pv, zv, want)) {
        __builtin_amdgcn_s_sleep(2);
        if ((uint32_t)(zv >> 32) != want) zv = ald64(zrd + zoC);
#pragma unroll
        for (int q = 0; q < 8; ++q)
          if ((pv[q] >> 16) != want) pv[q] = ald32(Pr + poC + (size_t)q * 512);
      }
      float hsum = 0.f;
#pragma unroll
      for (int q = 0; q < 8; ++q) hsum += f16b2f(pv[q]);
      float zf = __uint_as_float((uint32_t)zv);
      float htil = tanhf_(gh_c + hsum);
      float hn = fmaf(zf, htil - hreg, hreg);
      if (s == 0) out[(rb + (t - 1)) * 512 + T] = hn;
      hreg = hn;
      hA[T] = (_Float16)hn;
    }
    gh_c = gh_p;
    gz_c = gz_p;
    gr_c = gr_p;
    __syncthreads();  // B1: hA(t-1) visible
    if (t < 2047) {
      size_t r1 = rb + t + 1;
      gh_p = (float)ghg[r1 * 512 + T];
      if (sub == 0) {
        gz_p = (float)gzr[r1 * 1024 + gcol];
        gr_p = (float)gzr[r1 * 1024 + 512 + gcol];
      }
    }

    // ---- z/r GEMV: thread (c,sub) covers K rows {(cc*8+sub)*8..+8, cc=0..7} ----
    float za = 0.f, ra = 0.f;
#pragma unroll
    for (int cc = 0; cc < 8; ++cc) {
      uint4 hu = *(const uint4*)&hA[(cc * 8 + sub) * 8];
      uint4 wz = *(const uint4*)&wzK[(((cc)*64 + c) * 8 + sub) * 8];
      uint4 wr = *(const uint4*)&wzK[(((8 + cc) * 64 + c) * 8 + sub) * 8];
      za = dot2f(bc2(hu.x), bc2(wz.x), za); za = dot2f(bc2(hu.y), bc2(wz.y), za);
      za = dot2f(bc2(hu.z), bc2(wz.z), za); za = dot2f(bc2(hu.w), bc2(wz.w), za);
      ra = dot2f(bc2(hu.x), bc2(wr.x), ra); ra = dot2f(bc2(hu.y), bc2(wr.y), ra);
      ra = dot2f(bc2(hu.z), bc2(wr.z), ra); ra = dot2f(bc2(hu.w), bc2(wr.w), ra);
    }
    // wave-local reduce over sub (lanes differ only in low 3 bits)
#pragma unroll
    for (int d = 1; d < 8; d <<= 1) {
      za += __shfl_xor(za, d);
      ra += __shfl_xor(ra, d);
    }
    if (sub == 0) {
      float z = sigmoidf_(za + gz_c);
      float r = sigmoidf_(ra + gr_c);
      rh[c] = (_Float16)(r * (float)hA[gcol]);
      ast64(zm + zoN, ((uint64_t)tagN << 32) | (uint32_t)__float_as_uint(z));
    }
    __syncthreads();  // B2: rh ready

    // ---- candidate K-slice (own 64 rows) -> publish P (coalesced u32) ----
    {
      float pa = 0.f;
#pragma unroll
      for (int i = 0; i < 16; ++i) {
        uint2 ru = *(const uint2*)&rh[4 * i];  // broadcast
        pa = dot2f(bc2(ru.x), bc2(wh2[2 * i]), pa);
        pa = dot2f(bc2(ru.y), bc2(wh2[2 * i + 1]), pa);
      }
      unsigned short pb = __builtin_bit_cast(unsigned short, (_Float16)pa);
      ast32(Pm + poN, (tagN << 16) | (uint32_t)pb);
    }
    // pre-issue next combine loads (parity poN)
    zv = ald64(zrd + zoN);
#pragma unroll
    for (int q = 0; q < 8; ++q) pv[q] = ald32(Pr + poN + (size_t)q * 512);
    __builtin_amdgcn_sched_barrier(0);
  }

  // ---- epilogue: combine step 2047 (parity 1, tag 2048) ----
  {
    const uint32_t want = 2048u;
    while (!tagsok8(pv, zv, want)) {
      __builtin_amdgcn_s_sleep(2);
      if ((uint32_t)(zv >> 32) != want) zv = ald64(zrd + 16384);
#pragma unroll
      for (int q = 0; q < 8; ++q)
        if ((pv[q] >> 16) != want) pv[q] = ald32(Pr + 131072 + (size_t)q * 512);
    }
    float hsum = 0.f;
#pragma unroll
    for (int q = 0; q < 8; ++q) hsum += f16b2f(pv[q]);
    float zf = __uint_as_float((uint32_t)zv);
    float htil = tanhf_(gh_c + hsum);
    float hn = fmaf(zf, htil - hreg, hreg);
    if (s == 0) {
      out[(rb + 2047) * 512 + T] = hn;
      out[(size_t)32 * 2048 * 512 + (size_t)b * 512 + T] = hn;
    }
  }
}

// ---------------- Fallback scan (R8 scalar, !gh_mode) ----------------
__global__ __launch_bounds__(512) void gru_scan_fb(
    const float* __restrict__ x, const float* __restrict__ Wx,
    const float* __restrict__ Wh, const float* __restrict__ bias,
    const _Float16* gzr, float* out,
    uint64_t* __restrict__ Pbuf, uint64_t* __restrict__ zbuf) {
  __shared__ alignas(16) float zrp[2][8][64];
  __shared__ alignas(16) _Float16 wzrL[2 * 64 * 516];
  __shared__ alignas(16) _Float16 h16[512];
  __shared__ alignas(16) _Float16 rh16[64];
  __shared__ alignas(16) _Float16 x16s[64];

  const int T = threadIdx.x;
  const int bid = blockIdx.x;
  const int xcd = bid & 7, ii = bid >> 3;
  const int batch = xcd * 4 + (ii >> 3);
  const int slice = ii & 7;
  const int wv = T >> 6, ln = T & 63, n = T;
  {
    const int cc = T & 63, kb = T >> 6;
#pragma unroll 4
    for (int g = 0; g < 2; ++g) {
      const float* W = Wh + (size_t)g * 262144 + slice * 64 + cc;
      for (int i = 0; i < 64; ++i) {
        int k = kb + 8 * i;
        wzrL[(g * 64 + cc) * 516 + k] = (_Float16)W[(size_t)k * 512];
      }
    }
  }
  uint32_t wh2[32], wx2[32];
  {
    const float* Whh = Wh + 524288;
    const float* Wxh = Wx + 524288;
#pragma unroll
    for (int jj = 0; jj < 32; ++jj) {
      int kk = slice * 64 + 2 * jj;
      wh2[jj] = pk2u(Whh[(size_t)kk * 512 + n], Whh[(size_t)(kk + 1) * 512 + n]);
      wx2[jj] = pk2u(Wxh[(size_t)kk * 512 + n], Wxh[(size_t)(kk + 1) * 512 + n]);
    }
  }
  const float bh = bias[1024 + n];
  float hreg = 0.0f;
  h16[T] = (_Float16)0.0f;
  const size_t rowbase = (size_t)batch * 2048;
  float gz_p = 0.f, gr_p = 0.f, gz_cur = 0.f, gr_cur = 0.f, x_p = 0.f;
  if (T < 64)       gz_p = (float)gzr[rowbase * 1024 + slice * 64 + T];
  else if (T < 128) gr_p = (float)gzr[rowbase * 1024 + 512 + slice * 64 + (T - 64)];
  if (T < 64) x_p = x[rowbase * 512 + slice * 64 + T];

  uint64_t* Pmine = Pbuf + ((size_t)batch * 8 + slice) * 512 + n;
  const uint64_t* Pread = Pbuf + ((size_t)batch * 8) * 512 + n;
  uint64_t* zmine = zbuf + (size_t)batch * 512 + slice * 64 + ln;
  const uint64_t* zread = zbuf + (size_t)batch * 512 + n;

  for (int t = 0; t < 2048; ++t) {
    if (t > 0) {
      const size_t po = ((t - 1) & 1) ? 131072 : 0;
      const size_t zo = ((t - 1) & 1) ? 16384 : 0;
      const uint32_t want = (uint32_t)t;
      uint64_t v[8];
#pragma unroll
      for (int g = 0; g < 8; ++g) v[g] = ald64(Pread + po + (size_t)g * 512);
      uint64_t zvv = ald64(zread + zo);
      for (;;) {
        bool ok = true;
        if ((uint32_t)(zvv >> 32) != want) { zvv = ald64(zread + zo); ok = false; }
#pragma unroll
        for (int g = 0; g < 8; ++g)
          if ((uint32_t)(v[g] >> 32) != want) { v[g] = ald64(Pread + po + (size_t)g * 512); ok = false; }
        if (ok) break;
        __builtin_amdgcn_s_sleep(1);
      }
      float hsum = 0.f;
#pragma unroll
      for (int g = 0; g < 8; ++g) hsum += __uint_as_float((uint32_t)v[g]);
      float zf = __uint_as_float((uint32_t)zvv);
      float htil = tanhf_(bh + hsum);
      float hn = fmaf(zf, htil - hreg, hreg);
      if (slice == 0) out[(rowbase + (t - 1)) * 512 + n] = hn;
      hreg = hn;
      h16[T] = (_Float16)hn;
    }
    gz_cur = gz_p; gr_cur = gr_p;
    if (T < 64) x16s[T] = (_Float16)x_p;
    __syncthreads();
    if (t < 2047) {
      size_t r1 = rowbase + t + 1;
      if (T < 64)       gz_p = (float)gzr[r1 * 1024 + slice * 64 + T];
      else if (T < 128) gr_p = (float)gzr[r1 * 1024 + 512 + slice * 64 + (T - 64)];
      if (T < 64) x_p = x[r1 * 512 + slice * 64 + T];
    }
    float za = 0.f, ra = 0.f;
    {
      const _Float16* wzp = &wzrL[ln * 516 + 64 * wv];
      const _Float16* wrp = &wzrL[(64 + ln) * 516 + 64 * wv];
      const _Float16* hp = &h16[64 * wv];
#pragma unroll
      for (int jj = 0; jj < 16; ++jj) {
        uint2 wzu = *(const uint2*)(wzp + 4 * jj);
        uint2 wru = *(const uint2*)(wrp + 4 * jj);
        uint2 hu = *(const uint2*)(hp + 4 * jj);
        za = dot2f(bc2(hu.x), bc2(wzu.x), za);
        za = dot2f(bc2(hu.y), bc2(wzu.y), za);
        ra = dot2f(bc2(hu.x), bc2(wru.x), ra);
        ra = dot2f(bc2(hu.y), bc2(wru.y), ra);
      }
    }
    zrp[0][wv][ln] = za;
    zrp[1][wv][ln] = ra;
    __syncthreads();
    const size_t po = (t & 1) ? 131072 : 0;
    const size_t zo = (t & 1) ? 16384 : 0;
    const uint64_t tagw = ((uint64_t)(uint32_t)(t + 1)) << 32;
    if (T < 128) {
      const int g = T >> 6, cc = T & 63;
      float sum = 0.f;
#pragma unroll
      for (int s2 = 0; s2 < 8; ++s2) sum += zrp[g][s2][cc];
      if (g == 0) {
        float z = sigmoidf_(sum + gz_cur);
        ast64(zmine + zo, tagw | (uint32_t)__float_as_uint(z));
      } else {
        float r = sigmoidf_(sum + gr_cur);
        rh16[cc] = (_Float16)(r * (float)h16[slice * 64 + cc]);
      }
    }
    __syncthreads();
    float pa = 0.f;
#pragma unroll
    for (int jj = 0; jj < 16; ++jj) {
      uint2 ru = *(const uint2*)&rh16[4 * jj];
      pa = dot2f(bc2(ru.x), bc2(wh2[2 * jj]), pa);
      pa = dot2f(bc2(ru.y), bc2(wh2[2 * jj + 1]), pa);
    }
#pragma unroll
    for (int jj = 0; jj < 16; ++jj) {
      uint2 xu = *(const uint2*)&x16s[4 * jj];
      pa = dot2f(bc2(xu.x), bc2(wx2[2 * jj]), pa);
      pa = dot2f(bc2(xu.y), bc2(wx2[2 * jj + 1]), pa);
    }
    ast64(Pmine + po, tagw | (uint32_t)__float_as_uint(pa));
    __syncthreads();
  }
  {
    const uint32_t want = 2048u;
    uint64_t v[8];
#pragma unroll
    for (int g = 0; g < 8; ++g) v[g] = ald64(Pread + 131072 + (size_t)g * 512);
    uint64_t zvv = ald64(zread + 16384);
    for (;;) {
      bool ok = true;
      if ((uint32_t)(zvv >> 32) != want) { zvv = ald64(zread + 16384); ok = false; }
#pragma unroll
      for (int g = 0; g < 8; ++g)
        if ((uint32_t)(v[g] >> 32) != want) { v[g] = ald64(Pread + 131072 + (size_t)g * 512); ok = false; }
      if (ok) break;
      __builtin_amdgcn_s_sleep(1);
    }
    float hsum = 0.f;
#pragma unroll
    for (int g = 0; g < 8; ++g) hsum += __uint_as_float((uint32_t)v[g]);
    float zf = __uint_as_float((uint32_t)zvv);
    float htil = tanhf_(bh + hsum);
    float hn = fmaf(zf, htil - hreg, hreg);
    if (slice == 0) {
      out[(rowbase + 2047) * 512 + n] = hn;
      out[(size_t)32 * 2048 * 512 + (size_t)batch * 512 + n] = hn;
    }
  }
}

extern "C" void kernel_launch(void* const* d_in, const int* in_sizes, int n_in,
                              void* d_out, int out_size, void* d_ws, size_t ws_size,
                              hipStream_t stream) {
  (void)in_sizes; (void)n_in; (void)out_size;
  const float* x    = (const float*)d_in[0];
  const float* Wx   = (const float*)d_in[1];
  const float* Wh   = (const float*)d_in[2];
  const float* bias = (const float*)d_in[3];
  float* out = (float*)d_out;
  char* ws = (char*)d_ws;

  // gh_mode: Pbuf u32 [2][32][8][512] = 1 MB | zbuf u64 [2][32][512] = 256 KB | gh @ 2621440
  // fallback: Pbuf u64 2 MB | zbuf u64 @ 2097152
  uint32_t* Pbuf3 = (uint32_t*)ws;
  uint64_t* zbuf3 = (uint64_t*)(ws + 1048576);
  uint64_t* PbufF = (uint64_t*)ws;
  uint64_t* zbufF = (uint64_t*)(ws + 2097152);
  _Float16* gh    = (_Float16*)(ws + 2621440);

  hipMemsetAsync(ws, 0, 2621440, stream);  // reset exchange tags (replay-safe)
  const bool gh_mode = ws_size >= (size_t)2621440 + 67108864ull;
  if (gh_mode) {
    gemm_gx<<<512 * 12, 256, 0, stream>>>(x, Wx, bias, (_Float16*)d_out, gh, 12);
    gru_scan3<<<256, 512, 0, stream>>>((const _Float16*)d_out, gh, Wh, out,
                                       Pbuf3, zbuf3);
  } else {
    gemm_gx<<<512 * 8, 256, 0, stream>>>(x, Wx, bias, (_Float16*)d_out, gh, 8);
    gru_scan_fb<<<256, 512, 0, stream>>>(x, Wx, Wh, bias, (const _Float16*)d_out,
                                         out, PbufF, zbufF);
  }
}